// Round 5
// baseline (2079.437 us; speedup 1.0000x reference)
//
#include <hip/hip_runtime.h>

typedef unsigned short u16;
typedef unsigned int u32;
typedef __attribute__((ext_vector_type(8))) short short8;
typedef __attribute__((ext_vector_type(8))) unsigned short ushort8v;
typedef __attribute__((ext_vector_type(4))) float f32x4;

#define CDIM 128

__device__ __forceinline__ float b2f(u16 u){ return __uint_as_float(((unsigned)u)<<16); }
__device__ __forceinline__ u16 f2b(float f){
  unsigned x = __float_as_uint(f);
  unsigned r = (x + 0x7fffu + ((x>>16)&1u)) >> 16;
  return (u16)r;
}
__device__ __forceinline__ float wsum64(float v){
  #pragma unroll
  for(int d=1; d<64; d<<=1) v += __shfl_xor(v, d, 64);
  return v;
}
__device__ __forceinline__ float wsum16(float v){
  v += __shfl_xor(v, 1, 64);
  v += __shfl_xor(v, 2, 64);
  v += __shfl_xor(v, 4, 64);
  v += __shfl_xor(v, 8, 64);
  return v;
}

// ---------------- dtype probe ----------------
__global__ void k_probe(const u32* __restrict__ x, const u32* __restrict__ ei, int* __restrict__ flags){
  __shared__ int s_bf, s_nz;
  if(threadIdx.x == 0){ s_bf = 0; s_nz = 0; }
  __syncthreads();
  int c_bf = 0, c_nz = 0;
  for(int i = threadIdx.x; i < 4096; i += 256){
    u32 w = x[i];
    u32 e = (w >> 7) & 0xFFu;
    if(e >= 100u && e <= 140u) c_bf++;
    if(ei[2*i + 1] != 0u) c_nz++;
  }
  atomicAdd(&s_bf, c_bf);
  atomicAdd(&s_nz, c_nz);
  __syncthreads();
  if(threadIdx.x == 0){
    flags[0] = (s_bf < 2048) ? 1 : 0;
    flags[1] = (s_nz < 8) ? 1 : 0;
  }
}

// ---------------- conversions ----------------
__global__ void k_cvt_x(const void* __restrict__ src, u16* __restrict__ dst, int n,
                        const int* __restrict__ flags){
  int i = (blockIdx.x*256 + threadIdx.x)*8;
  if(i + 7 >= n) return;
  if(flags[0]){
    const float* s = (const float*)src + i;
    float4 a = *(const float4*)s;
    float4 b = *(const float4*)(s + 4);
    ushort8v o;
    o[0]=f2b(a.x); o[1]=f2b(a.y); o[2]=f2b(a.z); o[3]=f2b(a.w);
    o[4]=f2b(b.x); o[5]=f2b(b.y); o[6]=f2b(b.z); o[7]=f2b(b.w);
    *(ushort8v*)(dst + i) = o;
  } else {
    *(ushort8v*)(dst + i) = *(const ushort8v*)((const u16*)src + i);
  }
}

struct CvtArgs {
  const void* src[24];
  u16* dst[24];
  int n[24];
};

__global__ void k_cvt_params(CvtArgs a, const int* __restrict__ flags){
  int seg = blockIdx.y;
  int i = blockIdx.x*256 + threadIdx.x;
  int n = a.n[seg];
  if(i >= n) return;
  if(flags[0]) a.dst[seg][i] = f2b(((const float*)a.src[seg])[i]);
  else         a.dst[seg][i] = ((const u16*)a.src[seg])[i];
}

// convert edge index (int64->int32 if needed) + count destination degrees in the same pass
__global__ void k_cvt_ei_count(const int* __restrict__ src, int* __restrict__ dst, int E,
                               const int* __restrict__ flags, u32* __restrict__ cnt){
  int i = blockIdx.x*256 + threadIdx.x;
  if(i >= 2*E) return;
  int v = flags[1] ? src[2*i] : src[i];
  dst[i] = v;
  if(i >= E) atomicAdd(&cnt[v], 1u);
}

// ---------------- multi-block exclusive scan of cnt -> rowstart (+cursor, dinv) ----------------
__global__ __launch_bounds__(256) void k_scan1(const u32* __restrict__ cnt, int n, u32* __restrict__ bsum){
  const int lane = threadIdx.x & 63;
  const int wv = threadIdx.x >> 6;
  int i = blockIdx.x*256 + threadIdx.x;
  u32 v = (i < n) ? cnt[i] : 0u;
  #pragma unroll
  for(int d=1; d<64; d<<=1) v += (u32)__shfl_xor((int)v, d, 64);
  __shared__ u32 ws[4];
  if(lane == 0) ws[wv] = v;
  __syncthreads();
  if(threadIdx.x == 0) bsum[blockIdx.x] = ws[0] + ws[1] + ws[2] + ws[3];
}

__global__ __launch_bounds__(1024) void k_scan2(const u32* __restrict__ bsum, int nb, u32* __restrict__ bpre){
  __shared__ u32 s[1024];
  int t = threadIdx.x;
  u32 v = (t < nb) ? bsum[t] : 0u;
  s[t] = v;
  __syncthreads();
  for(int d=1; d<1024; d<<=1){
    u32 y = (t >= d) ? s[t-d] : 0u;
    __syncthreads();
    s[t] += y;
    __syncthreads();
  }
  if(t < nb) bpre[t] = s[t] - v;   // exclusive
}

__global__ __launch_bounds__(256) void k_scan3(const u32* __restrict__ cnt, int n,
                                               const u32* __restrict__ bpre,
                                               u32* __restrict__ rowstart, u32* __restrict__ cursor,
                                               float* __restrict__ dinv){
  const int lane = threadIdx.x & 63;
  const int wv = threadIdx.x >> 6;
  int i = blockIdx.x*256 + threadIdx.x;
  u32 v = (i < n) ? cnt[i] : 0u;
  u32 x = v;
  #pragma unroll
  for(int d=1; d<64; d<<=1){
    u32 y = (u32)__shfl_up((int)x, d, 64);
    if(lane >= d) x += y;
  }
  __shared__ u32 ws[4];
  if(lane == 63) ws[wv] = x;
  __syncthreads();
  u32 woff = 0;
  #pragma unroll
  for(int w=0; w<4; w++) if(w < wv) woff += ws[w];
  u32 incl = x + woff;
  u32 rs = bpre[blockIdx.x] + incl - v;
  if(i < n){
    rowstart[i] = rs;
    cursor[i] = rs;
    dinv[i] = rsqrtf((float)(v + 1u));
    if(i == n-1) rowstart[n] = rs + v;
  }
}

// ---------------- degree-bucket permutation (counting sort, 64 buckets) ----------------
// r5: DESCENDING degree order. r4's ascending order put all heavy nodes in the LAST
// blocks -> worst-case tail (occupancy 45%). Descending = heavy first, light nodes
// pack the tail. Offsets: dcur[b] = total - inclusive[b] = sum of buckets > b.
__global__ __launch_bounds__(256) void k_dhist(const u32* __restrict__ cnt, int n, u32* __restrict__ dbin){
  __shared__ u32 lh[64];
  if(threadIdx.x < 64) lh[threadIdx.x] = 0;
  __syncthreads();
  int i = blockIdx.x*256 + threadIdx.x;
  if(i < n){
    u32 b = cnt[i]; if(b > 63u) b = 63u;
    atomicAdd(&lh[b], 1u);
  }
  __syncthreads();
  if(threadIdx.x < 64){
    u32 c = lh[threadIdx.x];
    if(c) atomicAdd(&dbin[threadIdx.x], c);
  }
}

__global__ __launch_bounds__(64) void k_dscan(const u32* __restrict__ dbin, u32* __restrict__ dcur){
  int t = threadIdx.x;
  u32 v = dbin[t];
  u32 x = v;
  #pragma unroll
  for(int d=1; d<64; d<<=1){
    u32 y = (u32)__shfl_up((int)x, d, 64);
    if(t >= d) x += y;
  }
  u32 total = (u32)__shfl((int)x, 63, 64);
  dcur[t] = total - x;   // descending-order exclusive offset
}

__global__ __launch_bounds__(256) void k_dperm(const u32* __restrict__ cnt, int n, u32* __restrict__ dcur,
                        u32* __restrict__ perm){
  __shared__ u32 lh[64];
  __shared__ u32 lbase[64];
  if(threadIdx.x < 64) lh[threadIdx.x] = 0;
  __syncthreads();
  int i = blockIdx.x*256 + threadIdx.x;
  u32 b = 0, rank = 0;
  if(i < n){
    b = cnt[i]; if(b > 63u) b = 63u;
    rank = atomicAdd(&lh[b], 1u);
  }
  __syncthreads();
  if(threadIdx.x < 64){
    u32 c = lh[threadIdx.x];
    lbase[threadIdx.x] = c ? atomicAdd(&dcur[threadIdx.x], c) : 0u;
  }
  __syncthreads();
  if(i < n) perm[lbase[b] + rank] = (u32)i;
}

// ---------------- dst-range-partitioned scatter ----------------
__global__ __launch_bounds__(256) void k_scatter8(
  const int* __restrict__ ei, int E, int Nn, int nsl,
  u32* __restrict__ cursor, const float* __restrict__ dinv, int2* __restrict__ colw)
{
  const int r = blockIdx.x & 7;
  const int slice = blockIdx.x >> 3;
  const int q = (Nn + 7) >> 3;
  const int lo = r*q;
  const int hi = (lo + q < Nn) ? lo + q : Nn;
  const int chunk = (E + nsl - 1) / nsl;
  int e0 = slice*chunk;
  int e1 = e0 + chunk; if(e1 > E) e1 = E;
  for(int e = e0 + threadIdx.x; e < e1; e += 256){
    int d = ei[E + e];
    if(d >= lo && d < hi){
      int s = ei[e];
      u32 p = atomicAdd(&cursor[d], 1u);
      colw[p] = make_int2(s, __float_as_int(dinv[s]));
    }
  }
}

// ---------------- fused GEMM: 32 nodes/wave, weight by blockIdx.y,
//                  LDS-staged fully-coalesced stores ----------------
__global__ __launch_bounds__(256) void k_gemm3(
  const u16* __restrict__ A, int M,
  const u16* __restrict__ W0, const u16* __restrict__ bs0, int op0, u16* __restrict__ O0,
  const u16* __restrict__ W1, const u16* __restrict__ bs1, int op1, u16* __restrict__ O1,
  const u16* __restrict__ W2, const u16* __restrict__ bs2, int op2, u16* __restrict__ O2)
{
  __shared__ u16 stg[4][32][72];
  const int lane = threadIdx.x & 63;
  const int wv = threadIdx.x >> 6;
  const int l16 = lane & 15, quad = lane >> 4;
  const long nbase = (long)blockIdx.x*128 + wv*32;
  u16 (*st)[72] = stg[wv];

  const int w = blockIdx.y;
  const u16* Wm = (w==0) ? W0 : (w==1) ? W1 : W2;
  const u16* bp = (w==0) ? bs0 : (w==1) ? bs1 : bs2;
  const int  op = (w==0) ? op0 : (w==1) ? op1 : op2;
  u16*       Op = (w==0) ? O0 : (w==1) ? O1 : O2;

  short8 xf[2][4];             // B-operand: node nbase+nt*16+l16, k = quad*8 + kt*32
  #pragma unroll
  for(int nt=0; nt<2; nt++){
    long r = nbase + nt*16 + l16; if(r >= M) r = M-1;
    const u16* ap = A + r*CDIM + quad*8;
    #pragma unroll
    for(int kt=0; kt<4; kt++)
      xf[nt][kt] = *(const short8*)(ap + kt*32);
  }

  const int srow = lane >> 3;       // 0..7: row group for coalesced store
  const int schk = lane & 7;        // 16B chunk within 128B half-row

  #pragma unroll
  for(int half=0; half<2; half++){
    #pragma unroll
    for(int c2=0; c2<4; c2++){
      const int ct = half*4 + c2;
      f32x4 acc0 = {0.f,0.f,0.f,0.f}, acc1 = {0.f,0.f,0.f,0.f};
      const u16* wp = Wm + (ct*16 + l16)*CDIM + quad*8;   // A-operand: ch ct*16+l16
      #pragma unroll
      for(int kt=0; kt<4; kt++){
        short8 wf = *(const short8*)(wp + kt*32);
        acc0 = __builtin_amdgcn_mfma_f32_16x16x32_bf16(wf, xf[0][kt], acc0, 0, 0, 0);
        acc1 = __builtin_amdgcn_mfma_f32_16x16x32_bf16(wf, xf[1][kt], acc1, 0, 0, 0);
      }
      float bv[4] = {0.f,0.f,0.f,0.f};
      if(bp){
        ushort4 bq = *(const ushort4*)(bp + ct*16 + quad*4);
        bv[0]=b2f(bq.x); bv[1]=b2f(bq.y); bv[2]=b2f(bq.z); bv[3]=b2f(bq.w);
      }
      #pragma unroll
      for(int nt=0; nt<2; nt++){
        f32x4 a = nt ? acc1 : acc0;
        u16 o[4];
        #pragma unroll
        for(int g=0; g<4; g++){
          float v = a[g] + bv[g];
          if(op == 1) v = fmaxf(v, 0.f);
          else if(op == 2) v = 1.f/(1.f + __expf(-v));
          o[g] = f2b(v);
        }
        u32 p0 = (u32)o[0] | ((u32)o[1] << 16);
        u32 p1 = (u32)o[2] | ((u32)o[3] << 16);
        *(uint2*)&st[nt*16 + l16][c2*16 + quad*4] = make_uint2(p0, p1);
      }
    }
    // coalesced write-out of this 32-node x 64-ch half: full 128B segments
    #pragma unroll
    for(int i=0; i<4; i++){
      int row = i*8 + srow;
      long node = nbase + row;
      ushort8v v = *(const ushort8v*)&st[row][schk*8];
      if(node < M)
        *(ushort8v*)(Op + (size_t)node*CDIM + half*64 + schk*8) = v;
    }
  }
}

// ---------------- per-layer: quad-per-node gather, 2-deep pipelined (meta 2 ahead,
//                  rows 1 ahead) so L3 row latency overlaps the FMA block ----------------
__global__ __launch_bounds__(256) void k_layer_epi(
  const u16* __restrict__ xw, const u16* __restrict__ h, const u16* __restrict__ xl,
  const int2* __restrict__ colw, const u32* __restrict__ rowstart, const float* __restrict__ dinv,
  const u32* __restrict__ perm,
  const u16* __restrict__ bg, const u16* __restrict__ bng, const u16* __restrict__ bnb,
  const u16* __restrict__ bnrm, const u16* __restrict__ bnrv,
  const u16* __restrict__ lng, const u16* __restrict__ lnb,
  const u16* __restrict__ flng, const u16* __restrict__ flnb,
  float* __restrict__ xlocal, u16* __restrict__ xout, int n, int first, int final)
{
  const int lane = threadIdx.x & 63;
  const int quad = lane >> 4;
  const int l16 = lane & 15;
  const int wv = threadIdx.x >> 6;
  int idx = blockIdx.x*16 + wv*4 + quad;
  const int valid = (idx < n);
  int node = (int)perm[valid ? idx : (n-1)];
  const int cg = l16*8;                  // this lane's 8-channel strip
  u32 j0 = rowstart[node], j1 = rowstart[node+1];
  const int nch = (int)((j1 - j0 + 15u) >> 4);
  float a[8];
  #pragma unroll
  for(int g=0; g<8; g++) a[g] = 0.f;

  // pipeline state: pwA = meta chunk c (arrived), pwB = meta chunk c+1 (in flight),
  // va = rows of chunk c (in flight/arrived)
  int2 pwA = make_int2(0, 0), pwB = make_int2(0, 0);
  if(nch > 0 && l16 < (int)(j1 - j0)) pwA = colw[j0 + l16];
  if(nch > 1){
    u32 b1 = j0 + 16;
    if(l16 < (int)(j1 - b1)) pwB = colw[b1 + l16];
  }
  ushort8v va[16]; float wa[16];
  if(nch > 0){
    #pragma unroll
    for(int u=0; u<16; u++){
      int s = __shfl(pwA.x, quad*16 + u, 64);
      wa[u] = __int_as_float(__shfl(pwA.y, quad*16 + u, 64));
      va[u] = *(const ushort8v*)(xw + (size_t)s*CDIM + cg);
    }
  }
  for(int c = 0; c < nch; c++){
    // stage 1: issue meta for chunk c+2
    int2 pwC = make_int2(0, 0);
    u32 b2 = j0 + (u32)(c+2)*16;
    if(b2 < j1 && l16 < (int)(j1 - b2)) pwC = colw[b2 + l16];
    // stage 2: issue rows for chunk c+1 (meta pwB aged one full iteration)
    ushort8v vb[16]; float wb[16];
    if(c + 1 < nch){
      #pragma unroll
      for(int u=0; u<16; u++){
        int s = __shfl(pwB.x, quad*16 + u, 64);
        wb[u] = __int_as_float(__shfl(pwB.y, quad*16 + u, 64));
        vb[u] = *(const ushort8v*)(xw + (size_t)s*CDIM + cg);
      }
    }
    // stage 3: FMA on chunk c (rows aged one full iteration)
    #pragma unroll
    for(int u=0; u<16; u++){
      #pragma unroll
      for(int g=0; g<8; g++) a[g] = fmaf(wa[u], b2f(va[u][g]), a[g]);
    }
    if(c + 1 < nch){
      #pragma unroll
      for(int u=0; u<16; u++){ va[u] = vb[u]; wa[u] = wb[u]; }
    }
    pwB = pwC;
  }

  // ---- epilogue: 8 ch/lane, quad-local LN reductions ----
  float dn = dinv[node], sw = dn*dn;
  size_t nb = (size_t)node*CDIM + cg;
  ushort8v xwv  = *(const ushort8v*)(xw + nb);
  ushort8v xlv  = *(const ushort8v*)(xl + nb);
  ushort8v hv   = *(const ushort8v*)(h  + nb);
  ushort8v bgv  = *(const ushort8v*)(bg + cg);
  ushort8v bngv = *(const ushort8v*)(bng + cg);
  ushort8v bnbv = *(const ushort8v*)(bnb + cg);
  ushort8v bnrmv= *(const ushort8v*)(bnrm + cg);
  ushort8v bnrvv= *(const ushort8v*)(bnrv + cg);
  ushort8v lngv = *(const ushort8v*)(lng + cg);
  ushort8v lnbv = *(const ushort8v*)(lnb + cg);

  float x3[8], t[8];
  float ts = 0.f;
  #pragma unroll
  for(int g=0; g<8; g++){
    float x1 = a[g]*dn + b2f(xwv[g])*sw + b2f(bgv[g]) + b2f(xlv[g]);
    float sc = rsqrtf(b2f(bnrvv[g]) + 1e-5f) * b2f(bngv[g]);
    float x2 = (x1 - b2f(bnrmv[g]))*sc + b2f(bnbv[g]);
    x3[g] = fmaxf(x2, 0.f);
    t[g] = b2f(hv[g]) * x3[g];
    ts += t[g];
  }
  float mu = wsum16(ts) * (1.f/128.f);
  float vs = 0.f;
  #pragma unroll
  for(int g=0; g<8; g++){ float d = t[g] - mu; vs = fmaf(d, d, vs); }
  float inv = rsqrtf(wsum16(vs)*(1.f/128.f) + 1e-5f);

  float xn[8], xl2[8];
  #pragma unroll
  for(int g=0; g<8; g++){
    float y = (t[g] - mu)*inv*b2f(lngv[g]) + b2f(lnbv[g]);
    xn[g] = 0.1f*y + 0.9f*x3[g];
  }
  if(first){
    #pragma unroll
    for(int g=0; g<8; g++) xl2[g] = xn[g];
  } else {
    f32x4 p0 = *(const f32x4*)(xlocal + nb);
    f32x4 p1 = *(const f32x4*)(xlocal + nb + 4);
    xl2[0]=p0[0]+xn[0]; xl2[1]=p0[1]+xn[1]; xl2[2]=p0[2]+xn[2]; xl2[3]=p0[3]+xn[3];
    xl2[4]=p1[0]+xn[4]; xl2[5]=p1[1]+xn[5]; xl2[6]=p1[2]+xn[6]; xl2[7]=p1[3]+xn[7];
  }
  if(!final){
    if(valid){
      f32x4 q0 = {xl2[0],xl2[1],xl2[2],xl2[3]};
      f32x4 q1 = {xl2[4],xl2[5],xl2[6],xl2[7]};
      *(f32x4*)(xlocal + nb)     = q0;
      *(f32x4*)(xlocal + nb + 4) = q1;
      ushort8v o;
      #pragma unroll
      for(int g=0; g<8; g++) o[g] = f2b(xn[g]);
      *(ushort8v*)(xout + nb) = o;
    }
  } else {
    float ss = 0.f;
    #pragma unroll
    for(int g=0; g<8; g++) ss += xl2[g];
    float mu2 = wsum16(ss) * (1.f/128.f);
    float v2 = 0.f;
    #pragma unroll
    for(int g=0; g<8; g++){ float e = xl2[g] - mu2; v2 = fmaf(e, e, v2); }
    float inv2 = rsqrtf(wsum16(v2)*(1.f/128.f) + 1e-5f);
    ushort8v flngv = *(const ushort8v*)(flng + cg);
    ushort8v flnbv = *(const ushort8v*)(flnb + cg);
    if(valid){
      ushort8v o;
      #pragma unroll
      for(int g=0; g<8; g++)
        o[g] = f2b((xl2[g] - mu2)*inv2*b2f(flngv[g]) + b2f(flnbv[g]));
      *(ushort8v*)(xout + nb) = o;
    }
  }
}

// ---------------- kv = k^T v partials (+ k column sums) ----------------
__global__ __launch_bounds__(256) void k_kv(
  const u16* __restrict__ kk, const u16* __restrict__ vv, int n, int npb,
  float* __restrict__ part)
{
  __shared__ float sk[8][128];
  __shared__ float sv[8][128];
  const int tid = threadIdx.x;
  const int tr = tid >> 4, tc = tid & 15;
  float acc[8][8];
  #pragma unroll
  for(int i=0;i<8;i++){
    #pragma unroll
    for(int j=0;j<8;j++) acc[i][j] = 0.f;
  }
  float ks[8];
  #pragma unroll
  for(int i=0;i<8;i++) ks[i] = 0.f;
  int start = blockIdx.x * npb;
  int end = start + npb; if(end > n) end = n;
  const int lr = tid >> 5;
  const int lc = (tid & 31) * 4;
  for(int g0 = start; g0 < end; g0 += 8){
    int cnt = end - g0; if(cnt > 8) cnt = 8;
    __syncthreads();
    if(lr < cnt){
      ushort4 kq = *(const ushort4*)(kk + (size_t)(g0+lr)*CDIM + lc);
      ushort4 vq = *(const ushort4*)(vv + (size_t)(g0+lr)*CDIM + lc);
      sk[lr][lc] = b2f(kq.x); sk[lr][lc+1] = b2f(kq.y); sk[lr][lc+2] = b2f(kq.z); sk[lr][lc+3] = b2f(kq.w);
      sv[lr][lc] = b2f(vq.x); sv[lr][lc+1] = b2f(vq.y); sv[lr][lc+2] = b2f(vq.z); sv[lr][lc+3] = b2f(vq.w);
    }
    __syncthreads();
    for(int r=0; r<cnt; r++){
      float4 ka = *(const float4*)&sk[r][tr*8];
      float4 kb = *(const float4*)&sk[r][tr*8+4];
      float4 va = *(const float4*)&sv[r][tc*8];
      float4 vb = *(const float4*)&sv[r][tc*8+4];
      float kr[8] = {ka.x,ka.y,ka.z,ka.w,kb.x,kb.y,kb.z,kb.w};
      float vr[8] = {va.x,va.y,va.z,va.w,vb.x,vb.y,vb.z,vb.w};
      #pragma unroll
      for(int i=0;i<8;i++){
        #pragma unroll
        for(int j=0;j<8;j++) acc[i][j] = fmaf(kr[i], vr[j], acc[i][j]);
      }
      if(tc == 0){
        #pragma unroll
        for(int i=0;i<8;i++) ks[i] += kr[i];
      }
    }
  }
  float* p = part + (size_t)blockIdx.x * 16512;
  #pragma unroll
  for(int i=0;i<8;i++){
    #pragma unroll
    for(int j=0;j<8;j++)
      p[(size_t)(tc*8+j)*CDIM + tr*8 + i] = acc[i][j];
  }
  if(tc == 0){
    #pragma unroll
    for(int i=0;i<8;i++) p[16384 + tr*8 + i] = ks[i];
  }
}

// reduce partials -> Bext bf16 [144][128]
__global__ void k_kvred(const float* __restrict__ part, int nb, u16* __restrict__ Bext){
  int i = blockIdx.x*256 + threadIdx.x;
  if(i >= 144*128) return;
  float s = 0.f;
  if(i < 16512){
    #pragma unroll 8
    for(int b=0;b<nb;b++) s += part[(size_t)b*16512 + i];
  }
  Bext[i] = f2b(s);
}

// ---------------- fused attention tail ----------------
__global__ __launch_bounds__(256) void k_attn(
  const u16* __restrict__ q, const u16* __restrict__ Bext, const u16* __restrict__ hg,
  const u16* __restrict__ g, const u16* __restrict__ b,
  const u16* __restrict__ Wo, const u16* __restrict__ bo,
  const u16* __restrict__ Wp, const u16* __restrict__ bp,
  u16* __restrict__ xgout, void* __restrict__ outv,
  int M, int last, const int* __restrict__ flags)
{
  __shared__ u16 stg[4][32*136];
  const int lane = threadIdx.x & 63;
  const int wv = threadIdx.x >> 6;
  const int l16 = lane & 15, quad = lane >> 4;
  const long rbase = (long)blockIdx.x*128 + wv*32;
  u16* st = stg[wv];

  // ---- stage 1: num/den GEMM + LN -> y staged in LDS ----
  {
    short8 af[2][4];
    #pragma unroll
    for(int rt=0; rt<2; rt++){
      long r = rbase + rt*16 + l16; if(r >= M) r = M-1;
      const u16* ap = q + r*CDIM + quad*8;
      #pragma unroll
      for(int kt=0; kt<4; kt++)
        af[rt][kt] = *(const short8*)(ap + kt*32);
    }
    f32x4 acc[2][9];
    f32x4 zero = {0.f,0.f,0.f,0.f};
    #pragma unroll
    for(int rt=0; rt<2; rt++){
      #pragma unroll
      for(int ct=0; ct<9; ct++) acc[rt][ct] = zero;
    }
    #pragma unroll
    for(int ct=0; ct<9; ct++){
      const u16* wp = Bext + (ct*16 + l16)*CDIM + quad*8;
      #pragma unroll
      for(int kt=0; kt<4; kt++){
        short8 bf = *(const short8*)(wp + kt*32);
        acc[0][ct] = __builtin_amdgcn_mfma_f32_16x16x32_bf16(af[0][kt], bf, acc[0][ct], 0, 0, 0);
        acc[1][ct] = __builtin_amdgcn_mfma_f32_16x16x32_bf16(af[1][kt], bf, acc[1][ct], 0, 0, 0);
      }
    }
    #pragma unroll
    for(int rt=0; rt<2; rt++){
      float rden[4];
      #pragma unroll
      for(int gi=0; gi<4; gi++){
        float dv = __shfl(acc[rt][8][gi], lane & 48, 64);
        rden[gi] = 1.f/(dv + 1e-6f);
      }
      #pragma unroll
      for(int gi=0; gi<4; gi++){
        float sum = 0.f;
        #pragma unroll
        for(int ct=0; ct<8; ct++) sum += acc[rt][ct][gi]*rden[gi];
        float mu = wsum16(sum) * (1.f/128.f);
        float vs = 0.f;
        #pragma unroll
        for(int ct=0; ct<8; ct++){ float d = acc[rt][ct][gi]*rden[gi] - mu; vs = fmaf(d, d, vs); }
        float inv = rsqrtf(wsum16(vs)*(1.f/128.f) + 1e-5f);
        const int rowl = rt*16 + quad*4 + gi;
        #pragma unroll
        for(int ct=0; ct<8; ct++){
          int col = ct*16 + l16;
          float y = (acc[rt][ct][gi]*rden[gi] - mu)*inv*b2f(g[col]) + b2f(b[col]);
          st[rowl*136 + col] = f2b(y);
        }
      }
    }
  }
  // ---- stage 2: y *= (h + 0.9), coalesced hg reads, in-place in LDS ----
  #pragma unroll
  for(int p2=0; p2<8; p2++){
    int row = (p2>>2)*16 + (lane>>2);
    int seg = (lane&3) + (p2&3)*4;
    long node = rbase + row;
    if(node >= M) node = M-1;
    ushort8v yv = *(const ushort8v*)&st[row*136 + seg*8];
    ushort8v hv = *(const ushort8v*)(hg + (size_t)node*CDIM + seg*8);
    ushort8v o;
    #pragma unroll
    for(int i2=0; i2<8; i2++)
      o[i2] = f2b(b2f(yv[i2]) * (b2f(hv[i2]) + 0.9f));
    *(ushort8v*)&st[row*136 + seg*8] = o;
  }
  // ---- stage 3: p-fragments from LDS (B-operand layout) ----
  short8 pf[2][4];
  #pragma unroll
  for(int nt=0; nt<2; nt++){
    #pragma unroll
    for(int kt=0; kt<4; kt++)
      pf[nt][kt] = *(const short8*)&st[(nt*16 + l16)*136 + quad*8 + kt*32];
  }
  // ---- stage 4: out2 = relu(p @ Wo^T + bo), restaged into LDS ----
  #pragma unroll
  for(int ct=0; ct<8; ct++){
    f32x4 a0 = {0.f,0.f,0.f,0.f}, a1 = {0.f,0.f,0.f,0.f};
    const u16* wp = Wo + (ct*16 + l16)*CDIM + quad*8;
    #pragma unroll
    for(int kt=0; kt<4; kt++){
      short8 wf = *(const short8*)(wp + kt*32);
      a0 = __builtin_amdgcn_mfma_f32_16x16x32_bf16(wf, pf[0][kt], a0, 0, 0, 0);
      a1 = __builtin_amdgcn_mfma_f32_16x16x32_bf16(wf, pf[1][kt], a1, 0, 0, 0);
    }
    ushort4 bq = *(const ushort4*)(bo + ct*16 + quad*4);
    float bv[4] = {b2f(bq.x), b2f(bq.y), b2f(bq.z), b2f(bq.w)};
    #pragma unroll
    for(int nt=0; nt<2; nt++){
      f32x4 a = nt ? a1 : a0;
      u16 o[4];
      #pragma unroll
      for(int g2=0; g2<4; g2++)
        o[g2] = f2b(fmaxf(a[g2] + bv[g2], 0.f));
      u32 p0 = (u32)o[0] | ((u32)o[1] << 16);
      u32 p1 = (u32)o[2] | ((u32)o[3] << 16);
      *(uint2*)&st[(nt*16 + l16)*136 + ct*16 + quad*4] = make_uint2(p0, p1);
    }
  }
  if(!last){
    // ---- stage 5a: coalesced copy-out to xg ----
    #pragma unroll
    for(int p2=0; p2<8; p2++){
      int row = (p2>>2)*16 + (lane>>2);
      int seg = (lane&3) + (p2&3)*4;
      long node = rbase + row;
      ushort8v v = *(const ushort8v*)&st[row*136 + seg*8];
      if(node < M)
        *(ushort8v*)(xgout + (size_t)node*CDIM + seg*8) = v;
    }
  } else {
    // ---- stage 5b: final projection out = p2 @ Wp^T + bp (40 cols) ----
    const int f32m = flags[0];
    short8 pf2[2][4];
    #pragma unroll
    for(int nt=0; nt<2; nt++){
      #pragma unroll
      for(int kt=0; kt<4; kt++)
        pf2[nt][kt] = *(const short8*)&st[(nt*16 + l16)*136 + quad*8 + kt*32];
    }
    #pragma unroll
    for(int ct=0; ct<3; ct++){
      f32x4 a0 = {0.f,0.f,0.f,0.f}, a1 = {0.f,0.f,0.f,0.f};
      int wrow = ct*16 + l16; if(wrow > 39) wrow = 39;
      const u16* wp = Wp + wrow*CDIM + quad*8;
      #pragma unroll
      for(int kt=0; kt<4; kt++){
        short8 wf = *(const short8*)(wp + kt*32);
        a0 = __builtin_amdgcn_mfma_f32_16x16x32_bf16(wf, pf2[0][kt], a0, 0, 0, 0);
        a1 = __builtin_amdgcn_mfma_f32_16x16x32_bf16(wf, pf2[1][kt], a1, 0, 0, 0);
      }
      const int ch0 = ct*16 + quad*4;
      if(ch0 < 40){
        ushort4 bq = *(const ushort4*)(bp + ch0);
        float bv[4] = {b2f(bq.x), b2f(bq.y), b2f(bq.z), b2f(bq.w)};
        #pragma unroll
        for(int nt=0; nt<2; nt++){
          long node = rbase + nt*16 + l16;
          if(node < M){
            f32x4 a = nt ? a1 : a0;
            if(f32m){
              float* op = (float*)outv + node*40 + ch0;
              #pragma unroll
              for(int g2=0; g2<4; g2++) op[g2] = a[g2] + bv[g2];
            } else {
              u16 o[4];
              #pragma unroll
              for(int g2=0; g2<4; g2++) o[g2] = f2b(a[g2] + bv[g2]);
              u32 p0 = (u32)o[0] | ((u32)o[1] << 16);
              u32 p1 = (u32)o[2] | ((u32)o[3] << 16);
              *(uint2*)((u16*)outv + node*40 + ch0) = make_uint2(p0, p1);
            }
          }
        }
      }
    }
  }
}

extern "C" void kernel_launch(void* const* d_in, const int* in_sizes, int n_in,
                              void* d_out, int out_size, void* d_ws, size_t ws_size,
                              hipStream_t stream)
{
  (void)n_in;
  const int C = CDIM;
  const int Nn = in_sizes[0] / C;
  const int E  = in_sizes[1] / 2;

  char* ws = (char*)d_ws;
  size_t off = 0;
  auto alloc = [&](size_t bytes) -> char* {
    char* p = ws + off;
    off = (off + bytes + 255) & ~(size_t)255;
    return p;
  };
  u16*   x_cur  = (u16*)  alloc((size_t)Nn*C*2);     // also xg after final epi
  float* xlocal = (float*)alloc((size_t)Nn*C*4);     // early: [xb bf16 | eib]; then accum; then kvpart
  u16*   hb     = (u16*)  alloc((size_t)Nn*C*2);
  u16*   xwb    = (u16*)  alloc((size_t)Nn*C*2);
  u16*   xlb    = (u16*)  alloc((size_t)Nn*C*2);
  float* dinv   = (float*)alloc((size_t)Nn*4);
  u32*   cnt    = (u32*)  alloc((size_t)Nn*4);
  u32*   rowst  = (u32*)  alloc((size_t)(Nn+1)*4);
  u32*   cursor = (u32*)  alloc((size_t)Nn*4);
  u32*   perm   = (u32*)  alloc((size_t)Nn*4);
  int2*  colw   = (int2*) alloc((size_t)E*8);
  u16*   Bext   = (u16*)  alloc((size_t)144*128*2);
  int*   flags  = (int*)  alloc(256);
  u32*   bsum   = (u32*)  alloc(1024*4);
  u32*   bpre   = (u32*)  alloc(1024*4);
  u32*   dbin   = (u32*)  alloc(256);
  u32*   dcur   = (u32*)  alloc(256);
  size_t ptot = 0;
  for(int k=2;k<26;k++) ptot += (size_t)in_sizes[k];
  u16* pbuf = (u16*)alloc(ptot*2);

  if(off > ws_size){
    hipMemsetAsync(d_out, 0, (size_t)out_size*2, stream);
    return;
  }

  const u16* pp[26];
  {
    size_t po = 0;
    for(int k=2;k<26;k++){ pp[k] = pbuf + po; po += (size_t)in_sizes[k]; }
  }
  const u16* cWh  = pp[2];  const u16* cbh  = pp[3];
  const u16* cWg  = pp[4];  const u16* cbg  = pp[5];
  const u16* cWl  = pp[6];  const u16* cbl  = pp[7];
  const u16* clng = pp[8];  const u16* clnb = pp[9];
  const u16* cbng = pp[10]; const u16* cbnb = pp[11];
  const u16* cbnrm= pp[12]; const u16* cbnrv= pp[13];
  const u16* cgWh = pp[14]; const u16* cgbh = pp[15];
  const u16* cgWk = pp[16]; const u16* cgWv = pp[17];
  const u16* cglng= pp[18]; const u16* cglnb= pp[19];
  const u16* cgWo = pp[20]; const u16* cgbo = pp[21];
  const u16* cflng= pp[22]; const u16* cflnb= pp[23];
  const u16* cWp  = pp[24]; const u16* cbp  = pp[25];

  u16* xb  = (u16*)xlocal;                             // dead after first k_gemm3
  int* eib = (int*)((char*)xlocal + (size_t)Nn*C*2);   // dead after k_scatter8
  u16* xg  = x_cur;
  float* kvpart = xlocal;                              // 512*16512*4 = 33.8MB <= Nn*C*4

  const int NB_KV = 512;
  const int npb = (Nn + NB_KV - 1) / NB_KV;
  const int gblk = (Nn + 127) / 128;
  const int nodeblk = (Nn + 15) / 16;
  const int nscan = (Nn + 255) / 256;     // 391 for N=100k (must be <= 1024)
  const int nblk256 = (Nn + 255) / 256;
  const int NSL = 512;

  k_probe<<<1, 256, 0, stream>>>((const u32*)d_in[0], (const u32*)d_in[1], flags);
  hipMemsetAsync(cnt, 0, (size_t)Nn*4, stream);
  hipMemsetAsync(dbin, 0, 256, stream);
  k_cvt_ei_count<<<(2*E + 255)/256, 256, 0, stream>>>((const int*)d_in[1], eib, E, flags, cnt);
  k_cvt_x<<<(Nn*C/8 + 255)/256, 256, 0, stream>>>(d_in[0], xb, Nn*C, flags);
  {
    CvtArgs a;
    int maxn = 0;
    for(int k=2;k<26;k++){
      a.src[k-2] = d_in[k];
      a.dst[k-2] = (u16*)pp[k];
      a.n[k-2]   = in_sizes[k];
      if(in_sizes[k] > maxn) maxn = in_sizes[k];
    }
    dim3 g((maxn + 255)/256, 24);
    k_cvt_params<<<g, 256, 0, stream>>>(a, flags);
  }

  k_scan1<<<nscan, 256, 0, stream>>>(cnt, Nn, bsum);
  k_scan2<<<1, 1024, 0, stream>>>(bsum, nscan, bpre);
  k_scan3<<<nscan, 256, 0, stream>>>(cnt, Nn, bpre, rowst, cursor, dinv);
  k_dhist<<<nblk256, 256, 0, stream>>>(cnt, Nn, dbin);
  k_dscan<<<1, 64, 0, stream>>>(dbin, dcur);
  k_dperm<<<nblk256, 256, 0, stream>>>(cnt, Nn, dcur, perm);
  k_scatter8<<<NSL*8, 256, 0, stream>>>(eib, E, Nn, NSL, cursor, dinv, colw);

  const u16* xa = xb;
  for(int i=0; i<7; i++){
    k_gemm3<<<dim3(gblk,3), 256, 0, stream>>>(xa, Nn,
        cWh + (size_t)i*C*C, cbh + (size_t)i*C, 1, hb,
        cWg + (size_t)i*C*C, (const u16*)nullptr, 0, xwb,
        cWl + (size_t)i*C*C, cbl + (size_t)i*C, 0, xlb);
    k_layer_epi<<<nodeblk, 256, 0, stream>>>(xwb, hb, xlb, colw, rowst, dinv, perm,
        cbg + (size_t)i*C, cbng + (size_t)i*C, cbnb + (size_t)i*C,
        cbnrm + (size_t)i*C, cbnrv + (size_t)i*C,
        clng + (size_t)i*C, clnb + (size_t)i*C,
        cflng, cflnb,
        xlocal, x_cur, Nn, (i==0) ? 1 : 0, (i==6) ? 1 : 0);
    xa = x_cur;
  }

  for(int j=0; j<2; j++){
    k_gemm3<<<dim3(gblk,3), 256, 0, stream>>>(xg, Nn,
        cgWh + (size_t)j*C*C, cgbh + (size_t)j*C, 0, hb,
        cgWk + (size_t)j*C*C, (const u16*)nullptr, 2, xwb,
        cgWv + (size_t)j*C*C, (const u16*)nullptr, 0, xlb);
    k_kv   <<<NB_KV, 256, 0, stream>>>(xwb, xlb, Nn, npb, kvpart);
    k_kvred<<<(144*128 + 255)/256, 256, 0, stream>>>(kvpart, NB_KV, Bext);
    k_attn <<<gblk, 256, 0, stream>>>(xwb, Bext, hb,
        cglng + (size_t)j*C, cglnb + (size_t)j*C,
        cgWo + (size_t)j*C*C, cgbo + (size_t)j*C,
        cWp, cbp, xg, d_out, Nn, (j==1) ? 1 : 0, flags);
  }
}

// Round 6
// 1617.442 us; speedup vs baseline: 1.2856x; 1.2856x over previous
//
#include <hip/hip_runtime.h>

typedef unsigned short u16;
typedef unsigned int u32;
typedef __attribute__((ext_vector_type(8))) short short8;
typedef __attribute__((ext_vector_type(8))) unsigned short ushort8v;
typedef __attribute__((ext_vector_type(4))) float f32x4;

#define CDIM 128

__device__ __forceinline__ float b2f(u16 u){ return __uint_as_float(((unsigned)u)<<16); }
__device__ __forceinline__ u16 f2b(float f){
  unsigned x = __float_as_uint(f);
  unsigned r = (x + 0x7fffu + ((x>>16)&1u)) >> 16;
  return (u16)r;
}
__device__ __forceinline__ float wsum64(float v){
  #pragma unroll
  for(int d=1; d<64; d<<=1) v += __shfl_xor(v, d, 64);
  return v;
}
__device__ __forceinline__ float wsum16(float v){
  v += __shfl_xor(v, 1, 64);
  v += __shfl_xor(v, 2, 64);
  v += __shfl_xor(v, 4, 64);
  v += __shfl_xor(v, 8, 64);
  return v;
}

// ---------------- dtype probe ----------------
__global__ void k_probe(const u32* __restrict__ x, const u32* __restrict__ ei, int* __restrict__ flags){
  __shared__ int s_bf, s_nz;
  if(threadIdx.x == 0){ s_bf = 0; s_nz = 0; }
  __syncthreads();
  int c_bf = 0, c_nz = 0;
  for(int i = threadIdx.x; i < 4096; i += 256){
    u32 w = x[i];
    u32 e = (w >> 7) & 0xFFu;
    if(e >= 100u && e <= 140u) c_bf++;
    if(ei[2*i + 1] != 0u) c_nz++;
  }
  atomicAdd(&s_bf, c_bf);
  atomicAdd(&s_nz, c_nz);
  __syncthreads();
  if(threadIdx.x == 0){
    flags[0] = (s_bf < 2048) ? 1 : 0;
    flags[1] = (s_nz < 8) ? 1 : 0;
  }
}

// ---------------- conversions ----------------
__global__ void k_cvt_x(const void* __restrict__ src, u16* __restrict__ dst, int n,
                        const int* __restrict__ flags){
  int i = (blockIdx.x*256 + threadIdx.x)*8;
  if(i + 7 >= n) return;
  if(flags[0]){
    const float* s = (const float*)src + i;
    float4 a = *(const float4*)s;
    float4 b = *(const float4*)(s + 4);
    ushort8v o;
    o[0]=f2b(a.x); o[1]=f2b(a.y); o[2]=f2b(a.z); o[3]=f2b(a.w);
    o[4]=f2b(b.x); o[5]=f2b(b.y); o[6]=f2b(b.z); o[7]=f2b(b.w);
    *(ushort8v*)(dst + i) = o;
  } else {
    *(ushort8v*)(dst + i) = *(const ushort8v*)((const u16*)src + i);
  }
}

struct CvtArgs {
  const void* src[24];
  u16* dst[24];
  int n[24];
};

__global__ void k_cvt_params(CvtArgs a, const int* __restrict__ flags){
  int seg = blockIdx.y;
  int i = blockIdx.x*256 + threadIdx.x;
  int n = a.n[seg];
  if(i >= n) return;
  if(flags[0]) a.dst[seg][i] = f2b(((const float*)a.src[seg])[i]);
  else         a.dst[seg][i] = ((const u16*)a.src[seg])[i];
}

// convert edge index (int64->int32 if needed) + count destination degrees in the same pass
__global__ void k_cvt_ei_count(const int* __restrict__ src, int* __restrict__ dst, int E,
                               const int* __restrict__ flags, u32* __restrict__ cnt){
  int i = blockIdx.x*256 + threadIdx.x;
  if(i >= 2*E) return;
  int v = flags[1] ? src[2*i] : src[i];
  dst[i] = v;
  if(i >= E) atomicAdd(&cnt[v], 1u);
}

// ---------------- multi-block exclusive scan of cnt -> rowstart (+cursor, dinv) ----------------
__global__ __launch_bounds__(256) void k_scan1(const u32* __restrict__ cnt, int n, u32* __restrict__ bsum){
  const int lane = threadIdx.x & 63;
  const int wv = threadIdx.x >> 6;
  int i = blockIdx.x*256 + threadIdx.x;
  u32 v = (i < n) ? cnt[i] : 0u;
  #pragma unroll
  for(int d=1; d<64; d<<=1) v += (u32)__shfl_xor((int)v, d, 64);
  __shared__ u32 ws[4];
  if(lane == 0) ws[wv] = v;
  __syncthreads();
  if(threadIdx.x == 0) bsum[blockIdx.x] = ws[0] + ws[1] + ws[2] + ws[3];
}

__global__ __launch_bounds__(1024) void k_scan2(const u32* __restrict__ bsum, int nb, u32* __restrict__ bpre){
  __shared__ u32 s[1024];
  int t = threadIdx.x;
  u32 v = (t < nb) ? bsum[t] : 0u;
  s[t] = v;
  __syncthreads();
  for(int d=1; d<1024; d<<=1){
    u32 y = (t >= d) ? s[t-d] : 0u;
    __syncthreads();
    s[t] += y;
    __syncthreads();
  }
  if(t < nb) bpre[t] = s[t] - v;   // exclusive
}

__global__ __launch_bounds__(256) void k_scan3(const u32* __restrict__ cnt, int n,
                                               const u32* __restrict__ bpre,
                                               u32* __restrict__ rowstart, u32* __restrict__ cursor,
                                               float* __restrict__ dinv){
  const int lane = threadIdx.x & 63;
  const int wv = threadIdx.x >> 6;
  int i = blockIdx.x*256 + threadIdx.x;
  u32 v = (i < n) ? cnt[i] : 0u;
  u32 x = v;
  #pragma unroll
  for(int d=1; d<64; d<<=1){
    u32 y = (u32)__shfl_up((int)x, d, 64);
    if(lane >= d) x += y;
  }
  __shared__ u32 ws[4];
  if(lane == 63) ws[wv] = x;
  __syncthreads();
  u32 woff = 0;
  #pragma unroll
  for(int w=0; w<4; w++) if(w < wv) woff += ws[w];
  u32 incl = x + woff;
  u32 rs = bpre[blockIdx.x] + incl - v;
  if(i < n){
    rowstart[i] = rs;
    cursor[i] = rs;
    dinv[i] = rsqrtf((float)(v + 1u));
    if(i == n-1) rowstart[n] = rs + v;
  }
}

// ---------------- dst-range-partitioned scatter ----------------
__global__ __launch_bounds__(256) void k_scatter8(
  const int* __restrict__ ei, int E, int Nn, int nsl,
  u32* __restrict__ cursor, const float* __restrict__ dinv, int2* __restrict__ colw)
{
  const int r = blockIdx.x & 7;
  const int slice = blockIdx.x >> 3;
  const int q = (Nn + 7) >> 3;
  const int lo = r*q;
  const int hi = (lo + q < Nn) ? lo + q : Nn;
  const int chunk = (E + nsl - 1) / nsl;
  int e0 = slice*chunk;
  int e1 = e0 + chunk; if(e1 > E) e1 = E;
  for(int e = e0 + threadIdx.x; e < e1; e += 256){
    int d = ei[E + e];
    if(d >= lo && d < hi){
      int s = ei[e];
      u32 p = atomicAdd(&cursor[d], 1u);
      colw[p] = make_int2(s, __float_as_int(dinv[s]));
    }
  }
}

// ---------------- fused GEMM: 64 nodes/wave (nt=4 -> 4 indep acc chains per W-frag),
//                  y-parallel grid, LDS-staged full-line stores ----------------
// r6: r1 (nt=4, scatter stores) = 100us latency-bound; r4 (nt=2, staged stores) <=87us.
// Combine: nt=4 halves W-load instrs and gives 4-deep MFMA ILP; LDS staging keeps
// stores 128B-granular. LDS 36.9KB -> 4 blocks/CU by LDS; grid 391x3 x4w = 4.6 w/SIMD.
__global__ __launch_bounds__(256) void k_gemm3(
  const u16* __restrict__ A, int M,
  const u16* __restrict__ W0, const u16* __restrict__ bs0, int op0, u16* __restrict__ O0,
  const u16* __restrict__ W1, const u16* __restrict__ bs1, int op1, u16* __restrict__ O1,
  const u16* __restrict__ W2, const u16* __restrict__ bs2, int op2, u16* __restrict__ O2)
{
  __shared__ u16 stg[4][64][72];
  const int lane = threadIdx.x & 63;
  const int wv = threadIdx.x >> 6;
  const int l16 = lane & 15, quad = lane >> 4;
  const long nbase = (long)blockIdx.x*256 + wv*64;
  u16 (*st)[72] = stg[wv];

  const int w = blockIdx.y;
  const u16* Wm = (w==0) ? W0 : (w==1) ? W1 : W2;
  const u16* bp = (w==0) ? bs0 : (w==1) ? bs1 : bs2;
  const int  op = (w==0) ? op0 : (w==1) ? op1 : op2;
  u16*       Op = (w==0) ? O0 : (w==1) ? O1 : O2;

  short8 xf[4][4];             // B-operand: node nbase+nt*16+l16, k = quad*8 + kt*32
  #pragma unroll
  for(int nt=0; nt<4; nt++){
    long r = nbase + nt*16 + l16; if(r >= M) r = M-1;
    const u16* ap = A + r*CDIM + quad*8;
    #pragma unroll
    for(int kt=0; kt<4; kt++)
      xf[nt][kt] = *(const short8*)(ap + kt*32);
  }

  const int srow = lane >> 3;       // 0..7: row group for coalesced store
  const int schk = lane & 7;        // 16B chunk within 128B half-row

  #pragma unroll
  for(int half=0; half<2; half++){
    #pragma unroll
    for(int c2=0; c2<4; c2++){
      const int ct = half*4 + c2;
      f32x4 acc[4];
      #pragma unroll
      for(int nt=0; nt<4; nt++) acc[nt] = (f32x4){0.f,0.f,0.f,0.f};
      const u16* wp = Wm + (ct*16 + l16)*CDIM + quad*8;   // A-operand: ch ct*16+l16
      #pragma unroll
      for(int kt=0; kt<4; kt++){
        short8 wf = *(const short8*)(wp + kt*32);
        #pragma unroll
        for(int nt=0; nt<4; nt++)
          acc[nt] = __builtin_amdgcn_mfma_f32_16x16x32_bf16(wf, xf[nt][kt], acc[nt], 0, 0, 0);
      }
      float bv[4] = {0.f,0.f,0.f,0.f};
      if(bp){
        ushort4 bq = *(const ushort4*)(bp + ct*16 + quad*4);
        bv[0]=b2f(bq.x); bv[1]=b2f(bq.y); bv[2]=b2f(bq.z); bv[3]=b2f(bq.w);
      }
      #pragma unroll
      for(int nt=0; nt<4; nt++){
        u16 o[4];
        #pragma unroll
        for(int g=0; g<4; g++){
          float v = acc[nt][g] + bv[g];
          if(op == 1) v = fmaxf(v, 0.f);
          else if(op == 2) v = 1.f/(1.f + __expf(-v));
          o[g] = f2b(v);
        }
        u32 p0 = (u32)o[0] | ((u32)o[1] << 16);
        u32 p1 = (u32)o[2] | ((u32)o[3] << 16);
        *(uint2*)&st[nt*16 + l16][c2*16 + quad*4] = make_uint2(p0, p1);
      }
    }
    // coalesced write-out of this 64-node x 64-ch half: full 128B segments
    #pragma unroll
    for(int i=0; i<8; i++){
      int row = i*8 + srow;
      long node = nbase + row;
      ushort8v v = *(const ushort8v*)&st[row][schk*8];
      if(node < M)
        *(ushort8v*)(Op + (size_t)node*CDIM + half*64 + schk*8) = v;
    }
  }
}

// ---------------- per-layer: quad-per-node gather (r2-proven form: single buffer,
//                  natural order, VGPR ~40, occupancy ~55%) + quad-local epilogue ----------------
__global__ __launch_bounds__(256) void k_layer_epi(
  const u16* __restrict__ xw, const u16* __restrict__ h, const u16* __restrict__ xl,
  const int2* __restrict__ colw, const u32* __restrict__ rowstart, const float* __restrict__ dinv,
  const u16* __restrict__ bg, const u16* __restrict__ bng, const u16* __restrict__ bnb,
  const u16* __restrict__ bnrm, const u16* __restrict__ bnrv,
  const u16* __restrict__ lng, const u16* __restrict__ lnb,
  const u16* __restrict__ flng, const u16* __restrict__ flnb,
  float* __restrict__ xlocal, u16* __restrict__ xout, int n, int first, int final)
{
  const int lane = threadIdx.x & 63;
  const int quad = lane >> 4;
  const int l16 = lane & 15;
  const int wv = threadIdx.x >> 6;
  int node = blockIdx.x*16 + wv*4 + quad;
  const int valid = (node < n);
  if(!valid) node = n - 1;
  const int cg = l16*8;                  // this lane's 8-channel strip
  u32 j0 = rowstart[node], j1 = rowstart[node+1];
  float a[8];
  #pragma unroll
  for(int g=0; g<8; g++) a[g] = 0.f;

  for(u32 base = j0; base < j1; base += 16){
    int cnt = (int)(j1 - base); if(cnt > 16) cnt = 16;
    int2 pw = make_int2(0, 0);           // pad: src 0 (valid row, L1-hot), w = +0.0f
    if(l16 < cnt) pw = colw[base + l16];
    ushort8v v[16]; float w[16];
    #pragma unroll
    for(int u=0; u<16; u++){
      int s = __shfl(pw.x, quad*16 + u, 64);
      w[u] = __int_as_float(__shfl(pw.y, quad*16 + u, 64));
      v[u] = *(const ushort8v*)(xw + (size_t)s*CDIM + cg);
    }
    #pragma unroll
    for(int u=0; u<16; u++){
      #pragma unroll
      for(int g=0; g<8; g++) a[g] = fmaf(w[u], b2f(v[u][g]), a[g]);
    }
  }

  // ---- epilogue: 8 ch/lane, quad-local LN reductions ----
  float dn = dinv[node], sw = dn*dn;
  size_t nb = (size_t)node*CDIM + cg;
  ushort8v xwv  = *(const ushort8v*)(xw + nb);
  ushort8v xlv  = *(const ushort8v*)(xl + nb);
  ushort8v hv   = *(const ushort8v*)(h  + nb);
  ushort8v bgv  = *(const ushort8v*)(bg + cg);
  ushort8v bngv = *(const ushort8v*)(bng + cg);
  ushort8v bnbv = *(const ushort8v*)(bnb + cg);
  ushort8v bnrmv= *(const ushort8v*)(bnrm + cg);
  ushort8v bnrvv= *(const ushort8v*)(bnrv + cg);
  ushort8v lngv = *(const ushort8v*)(lng + cg);
  ushort8v lnbv = *(const ushort8v*)(lnb + cg);

  float x3[8], t[8];
  float ts = 0.f;
  #pragma unroll
  for(int g=0; g<8; g++){
    float x1 = a[g]*dn + b2f(xwv[g])*sw + b2f(bgv[g]) + b2f(xlv[g]);
    float sc = rsqrtf(b2f(bnrvv[g]) + 1e-5f) * b2f(bngv[g]);
    float x2 = (x1 - b2f(bnrmv[g]))*sc + b2f(bnbv[g]);
    x3[g] = fmaxf(x2, 0.f);
    t[g] = b2f(hv[g]) * x3[g];
    ts += t[g];
  }
  float mu = wsum16(ts) * (1.f/128.f);
  float vs = 0.f;
  #pragma unroll
  for(int g=0; g<8; g++){ float d = t[g] - mu; vs = fmaf(d, d, vs); }
  float inv = rsqrtf(wsum16(vs)*(1.f/128.f) + 1e-5f);

  float xn[8], xl2[8];
  #pragma unroll
  for(int g=0; g<8; g++){
    float y = (t[g] - mu)*inv*b2f(lngv[g]) + b2f(lnbv[g]);
    xn[g] = 0.1f*y + 0.9f*x3[g];
  }
  if(first){
    #pragma unroll
    for(int g=0; g<8; g++) xl2[g] = xn[g];
  } else {
    f32x4 p0 = *(const f32x4*)(xlocal + nb);
    f32x4 p1 = *(const f32x4*)(xlocal + nb + 4);
    xl2[0]=p0[0]+xn[0]; xl2[1]=p0[1]+xn[1]; xl2[2]=p0[2]+xn[2]; xl2[3]=p0[3]+xn[3];
    xl2[4]=p1[0]+xn[4]; xl2[5]=p1[1]+xn[5]; xl2[6]=p1[2]+xn[6]; xl2[7]=p1[3]+xn[7];
  }
  if(!final){
    if(valid){
      f32x4 q0 = {xl2[0],xl2[1],xl2[2],xl2[3]};
      f32x4 q1 = {xl2[4],xl2[5],xl2[6],xl2[7]};
      *(f32x4*)(xlocal + nb)     = q0;
      *(f32x4*)(xlocal + nb + 4) = q1;
      ushort8v o;
      #pragma unroll
      for(int g=0; g<8; g++) o[g] = f2b(xn[g]);
      *(ushort8v*)(xout + nb) = o;
    }
  } else {
    float ss = 0.f;
    #pragma unroll
    for(int g=0; g<8; g++) ss += xl2[g];
    float mu2 = wsum16(ss) * (1.f/128.f);
    float v2 = 0.f;
    #pragma unroll
    for(int g=0; g<8; g++){ float e = xl2[g] - mu2; v2 = fmaf(e, e, v2); }
    float inv2 = rsqrtf(wsum16(v2)*(1.f/128.f) + 1e-5f);
    ushort8v flngv = *(const ushort8v*)(flng + cg);
    ushort8v flnbv = *(const ushort8v*)(flnb + cg);
    if(valid){
      ushort8v o;
      #pragma unroll
      for(int g=0; g<8; g++)
        o[g] = f2b((xl2[g] - mu2)*inv2*b2f(flngv[g]) + b2f(flnbv[g]));
      *(ushort8v*)(xout + nb) = o;
    }
  }
}

// ---------------- kv = k^T v partials (+ k column sums) ----------------
__global__ __launch_bounds__(256) void k_kv(
  const u16* __restrict__ kk, const u16* __restrict__ vv, int n, int npb,
  float* __restrict__ part)
{
  __shared__ float sk[8][128];
  __shared__ float sv[8][128];
  const int tid = threadIdx.x;
  const int tr = tid >> 4, tc = tid & 15;
  float acc[8][8];
  #pragma unroll
  for(int i=0;i<8;i++){
    #pragma unroll
    for(int j=0;j<8;j++) acc[i][j] = 0.f;
  }
  float ks[8];
  #pragma unroll
  for(int i=0;i<8;i++) ks[i] = 0.f;
  int start = blockIdx.x * npb;
  int end = start + npb; if(end > n) end = n;
  const int lr = tid >> 5;
  const int lc = (tid & 31) * 4;
  for(int g0 = start; g0 < end; g0 += 8){
    int cnt = end - g0; if(cnt > 8) cnt = 8;
    __syncthreads();
    if(lr < cnt){
      ushort4 kq = *(const ushort4*)(kk + (size_t)(g0+lr)*CDIM + lc);
      ushort4 vq = *(const ushort4*)(vv + (size_t)(g0+lr)*CDIM + lc);
      sk[lr][lc] = b2f(kq.x); sk[lr][lc+1] = b2f(kq.y); sk[lr][lc+2] = b2f(kq.z); sk[lr][lc+3] = b2f(kq.w);
      sv[lr][lc] = b2f(vq.x); sv[lr][lc+1] = b2f(vq.y); sv[lr][lc+2] = b2f(vq.z); sv[lr][lc+3] = b2f(vq.w);
    }
    __syncthreads();
    for(int r=0; r<cnt; r++){
      float4 ka = *(const float4*)&sk[r][tr*8];
      float4 kb = *(const float4*)&sk[r][tr*8+4];
      float4 va = *(const float4*)&sv[r][tc*8];
      float4 vb = *(const float4*)&sv[r][tc*8+4];
      float kr[8] = {ka.x,ka.y,ka.z,ka.w,kb.x,kb.y,kb.z,kb.w};
      float vr[8] = {va.x,va.y,va.z,va.w,vb.x,vb.y,vb.z,vb.w};
      #pragma unroll
      for(int i=0;i<8;i++){
        #pragma unroll
        for(int j=0;j<8;j++) acc[i][j] = fmaf(kr[i], vr[j], acc[i][j]);
      }
      if(tc == 0){
        #pragma unroll
        for(int i=0;i<8;i++) ks[i] += kr[i];
      }
    }
  }
  float* p = part + (size_t)blockIdx.x * 16512;
  #pragma unroll
  for(int i=0;i<8;i++){
    #pragma unroll
    for(int j=0;j<8;j++)
      p[(size_t)(tc*8+j)*CDIM + tr*8 + i] = acc[i][j];
  }
  if(tc == 0){
    #pragma unroll
    for(int i=0;i<8;i++) p[16384 + tr*8 + i] = ks[i];
  }
}

// reduce partials -> Bext bf16 [144][128]
__global__ void k_kvred(const float* __restrict__ part, int nb, u16* __restrict__ Bext){
  int i = blockIdx.x*256 + threadIdx.x;
  if(i >= 144*128) return;
  float s = 0.f;
  if(i < 16512){
    #pragma unroll 8
    for(int b=0;b<nb;b++) s += part[(size_t)b*16512 + i];
  }
  Bext[i] = f2b(s);
}

// ---------------- fused attention tail ----------------
__global__ __launch_bounds__(256) void k_attn(
  const u16* __restrict__ q, const u16* __restrict__ Bext, const u16* __restrict__ hg,
  const u16* __restrict__ g, const u16* __restrict__ b,
  const u16* __restrict__ Wo, const u16* __restrict__ bo,
  const u16* __restrict__ Wp, const u16* __restrict__ bp,
  u16* __restrict__ xgout, void* __restrict__ outv,
  int M, int last, const int* __restrict__ flags)
{
  __shared__ u16 stg[4][32*136];
  const int lane = threadIdx.x & 63;
  const int wv = threadIdx.x >> 6;
  const int l16 = lane & 15, quad = lane >> 4;
  const long rbase = (long)blockIdx.x*128 + wv*32;
  u16* st = stg[wv];

  // ---- stage 1: num/den GEMM + LN -> y staged in LDS ----
  {
    short8 af[2][4];
    #pragma unroll
    for(int rt=0; rt<2; rt++){
      long r = rbase + rt*16 + l16; if(r >= M) r = M-1;
      const u16* ap = q + r*CDIM + quad*8;
      #pragma unroll
      for(int kt=0; kt<4; kt++)
        af[rt][kt] = *(const short8*)(ap + kt*32);
    }
    f32x4 acc[2][9];
    f32x4 zero = {0.f,0.f,0.f,0.f};
    #pragma unroll
    for(int rt=0; rt<2; rt++){
      #pragma unroll
      for(int ct=0; ct<9; ct++) acc[rt][ct] = zero;
    }
    #pragma unroll
    for(int ct=0; ct<9; ct++){
      const u16* wp = Bext + (ct*16 + l16)*CDIM + quad*8;
      #pragma unroll
      for(int kt=0; kt<4; kt++){
        short8 bf = *(const short8*)(wp + kt*32);
        acc[0][ct] = __builtin_amdgcn_mfma_f32_16x16x32_bf16(af[0][kt], bf, acc[0][ct], 0, 0, 0);
        acc[1][ct] = __builtin_amdgcn_mfma_f32_16x16x32_bf16(af[1][kt], bf, acc[1][ct], 0, 0, 0);
      }
    }
    #pragma unroll
    for(int rt=0; rt<2; rt++){
      float rden[4];
      #pragma unroll
      for(int gi=0; gi<4; gi++){
        float dv = __shfl(acc[rt][8][gi], lane & 48, 64);
        rden[gi] = 1.f/(dv + 1e-6f);
      }
      #pragma unroll
      for(int gi=0; gi<4; gi++){
        float sum = 0.f;
        #pragma unroll
        for(int ct=0; ct<8; ct++) sum += acc[rt][ct][gi]*rden[gi];
        float mu = wsum16(sum) * (1.f/128.f);
        float vs = 0.f;
        #pragma unroll
        for(int ct=0; ct<8; ct++){ float d = acc[rt][ct][gi]*rden[gi] - mu; vs = fmaf(d, d, vs); }
        float inv = rsqrtf(wsum16(vs)*(1.f/128.f) + 1e-5f);
        const int rowl = rt*16 + quad*4 + gi;
        #pragma unroll
        for(int ct=0; ct<8; ct++){
          int col = ct*16 + l16;
          float y = (acc[rt][ct][gi]*rden[gi] - mu)*inv*b2f(g[col]) + b2f(b[col]);
          st[rowl*136 + col] = f2b(y);
        }
      }
    }
  }
  // ---- stage 2: y *= (h + 0.9), coalesced hg reads, in-place in LDS ----
  #pragma unroll
  for(int p2=0; p2<8; p2++){
    int row = (p2>>2)*16 + (lane>>2);
    int seg = (lane&3) + (p2&3)*4;
    long node = rbase + row;
    if(node >= M) node = M-1;
    ushort8v yv = *(const ushort8v*)&st[row*136 + seg*8];
    ushort8v hv = *(const ushort8v*)(hg + (size_t)node*CDIM + seg*8);
    ushort8v o;
    #pragma unroll
    for(int i2=0; i2<8; i2++)
      o[i2] = f2b(b2f(yv[i2]) * (b2f(hv[i2]) + 0.9f));
    *(ushort8v*)&st[row*136 + seg*8] = o;
  }
  // ---- stage 3: p-fragments from LDS (B-operand layout) ----
  short8 pf[2][4];
  #pragma unroll
  for(int nt=0; nt<2; nt++){
    #pragma unroll
    for(int kt=0; kt<4; kt++)
      pf[nt][kt] = *(const short8*)&st[(nt*16 + l16)*136 + quad*8 + kt*32];
  }
  // ---- stage 4: out2 = relu(p @ Wo^T + bo), restaged into LDS ----
  #pragma unroll
  for(int ct=0; ct<8; ct++){
    f32x4 a0 = {0.f,0.f,0.f,0.f}, a1 = {0.f,0.f,0.f,0.f};
    const u16* wp = Wo + (ct*16 + l16)*CDIM + quad*8;
    #pragma unroll
    for(int kt=0; kt<4; kt++){
      short8 wf = *(const short8*)(wp + kt*32);
      a0 = __builtin_amdgcn_mfma_f32_16x16x32_bf16(wf, pf[0][kt], a0, 0, 0, 0);
      a1 = __builtin_amdgcn_mfma_f32_16x16x32_bf16(wf, pf[1][kt], a1, 0, 0, 0);
    }
    ushort4 bq = *(const ushort4*)(bo + ct*16 + quad*4);
    float bv[4] = {b2f(bq.x), b2f(bq.y), b2f(bq.z), b2f(bq.w)};
    #pragma unroll
    for(int nt=0; nt<2; nt++){
      f32x4 a = nt ? a1 : a0;
      u16 o[4];
      #pragma unroll
      for(int g2=0; g2<4; g2++)
        o[g2] = f2b(fmaxf(a[g2] + bv[g2], 0.f));
      u32 p0 = (u32)o[0] | ((u32)o[1] << 16);
      u32 p1 = (u32)o[2] | ((u32)o[3] << 16);
      *(uint2*)&st[(nt*16 + l16)*136 + ct*16 + quad*4] = make_uint2(p0, p1);
    }
  }
  if(!last){
    // ---- stage 5a: coalesced copy-out to xg ----
    #pragma unroll
    for(int p2=0; p2<8; p2++){
      int row = (p2>>2)*16 + (lane>>2);
      int seg = (lane&3) + (p2&3)*4;
      long node = rbase + row;
      ushort8v v = *(const ushort8v*)&st[row*136 + seg*8];
      if(node < M)
        *(ushort8v*)(xgout + (size_t)node*CDIM + seg*8) = v;
    }
  } else {
    // ---- stage 5b: final projection out = p2 @ Wp^T + bp (40 cols) ----
    const int f32m = flags[0];
    short8 pf2[2][4];
    #pragma unroll
    for(int nt=0; nt<2; nt++){
      #pragma unroll
      for(int kt=0; kt<4; kt++)
        pf2[nt][kt] = *(const short8*)&st[(nt*16 + l16)*136 + quad*8 + kt*32];
    }
    #pragma unroll
    for(int ct=0; ct<3; ct++){
      f32x4 a0 = {0.f,0.f,0.f,0.f}, a1 = {0.f,0.f,0.f,0.f};
      int wrow = ct*16 + l16; if(wrow > 39) wrow = 39;
      const u16* wp = Wp + wrow*CDIM + quad*8;
      #pragma unroll
      for(int kt=0; kt<4; kt++){
        short8 wf = *(const short8*)(wp + kt*32);
        a0 = __builtin_amdgcn_mfma_f32_16x16x32_bf16(wf, pf2[0][kt], a0, 0, 0, 0);
        a1 = __builtin_amdgcn_mfma_f32_16x16x32_bf16(wf, pf2[1][kt], a1, 0, 0, 0);
      }
      const int ch0 = ct*16 + quad*4;
      if(ch0 < 40){
        ushort4 bq = *(const ushort4*)(bp + ch0);
        float bv[4] = {b2f(bq.x), b2f(bq.y), b2f(bq.z), b2f(bq.w)};
        #pragma unroll
        for(int nt=0; nt<2; nt++){
          long node = rbase + nt*16 + l16;
          if(node < M){
            f32x4 a = nt ? a1 : a0;
            if(f32m){
              float* op = (float*)outv + node*40 + ch0;
              #pragma unroll
              for(int g2=0; g2<4; g2++) op[g2] = a[g2] + bv[g2];
            } else {
              u16 o[4];
              #pragma unroll
              for(int g2=0; g2<4; g2++) o[g2] = f2b(a[g2] + bv[g2]);
              u32 p0 = (u32)o[0] | ((u32)o[1] << 16);
              u32 p1 = (u32)o[2] | ((u32)o[3] << 16);
              *(uint2*)((u16*)outv + node*40 + ch0) = make_uint2(p0, p1);
            }
          }
        }
      }
    }
  }
}

extern "C" void kernel_launch(void* const* d_in, const int* in_sizes, int n_in,
                              void* d_out, int out_size, void* d_ws, size_t ws_size,
                              hipStream_t stream)
{
  (void)n_in;
  const int C = CDIM;
  const int Nn = in_sizes[0] / C;
  const int E  = in_sizes[1] / 2;

  char* ws = (char*)d_ws;
  size_t off = 0;
  auto alloc = [&](size_t bytes) -> char* {
    char* p = ws + off;
    off = (off + bytes + 255) & ~(size_t)255;
    return p;
  };
  u16*   x_cur  = (u16*)  alloc((size_t)Nn*C*2);     // also xg after final epi
  float* xlocal = (float*)alloc((size_t)Nn*C*4);     // early: [xb bf16 | eib]; then accum; then kvpart
  u16*   hb     = (u16*)  alloc((size_t)Nn*C*2);
  u16*   xwb    = (u16*)  alloc((size_t)Nn*C*2);
  u16*   xlb    = (u16*)  alloc((size_t)Nn*C*2);
  float* dinv   = (float*)alloc((size_t)Nn*4);
  u32*   cnt    = (u32*)  alloc((size_t)Nn*4);
  u32*   rowst  = (u32*)  alloc((size_t)(Nn+1)*4);
  u32*   cursor = (u32*)  alloc((size_t)Nn*4);
  int2*  colw   = (int2*) alloc((size_t)E*8);
  u16*   Bext   = (u16*)  alloc((size_t)144*128*2);
  int*   flags  = (int*)  alloc(256);
  u32*   bsum   = (u32*)  alloc(1024*4);
  u32*   bpre   = (u32*)  alloc(1024*4);
  size_t ptot = 0;
  for(int k=2;k<26;k++) ptot += (size_t)in_sizes[k];
  u16* pbuf = (u16*)alloc(ptot*2);

  if(off > ws_size){
    hipMemsetAsync(d_out, 0, (size_t)out_size*2, stream);
    return;
  }

  const u16* pp[26];
  {
    size_t po = 0;
    for(int k=2;k<26;k++){ pp[k] = pbuf + po; po += (size_t)in_sizes[k]; }
  }
  const u16* cWh  = pp[2];  const u16* cbh  = pp[3];
  const u16* cWg  = pp[4];  const u16* cbg  = pp[5];
  const u16* cWl  = pp[6];  const u16* cbl  = pp[7];
  const u16* clng = pp[8];  const u16* clnb = pp[9];
  const u16* cbng = pp[10]; const u16* cbnb = pp[11];
  const u16* cbnrm= pp[12]; const u16* cbnrv= pp[13];
  const u16* cgWh = pp[14]; const u16* cgbh = pp[15];
  const u16* cgWk = pp[16]; const u16* cgWv = pp[17];
  const u16* cglng= pp[18]; const u16* cglnb= pp[19];
  const u16* cgWo = pp[20]; const u16* cgbo = pp[21];
  const u16* cflng= pp[22]; const u16* cflnb= pp[23];
  const u16* cWp  = pp[24]; const u16* cbp  = pp[25];

  u16* xb  = (u16*)xlocal;                             // dead after first k_gemm3
  int* eib = (int*)((char*)xlocal + (size_t)Nn*C*2);   // dead after k_scatter8
  u16* xg  = x_cur;
  float* kvpart = xlocal;                              // 512*16512*4 = 33.8MB <= Nn*C*4

  const int NB_KV = 512;
  const int npb = (Nn + NB_KV - 1) / NB_KV;
  const int gblk = (Nn + 127) / 128;
  const int gblk4 = (Nn + 255) / 256;
  const int nodeblk = (Nn + 15) / 16;
  const int nscan = (Nn + 255) / 256;     // 391 for N=100k (must be <= 1024)
  const int NSL = 512;

  k_probe<<<1, 256, 0, stream>>>((const u32*)d_in[0], (const u32*)d_in[1], flags);
  hipMemsetAsync(cnt, 0, (size_t)Nn*4, stream);
  k_cvt_ei_count<<<(2*E + 255)/256, 256, 0, stream>>>((const int*)d_in[1], eib, E, flags, cnt);
  k_cvt_x<<<(Nn*C/8 + 255)/256, 256, 0, stream>>>(d_in[0], xb, Nn*C, flags);
  {
    CvtArgs a;
    int maxn = 0;
    for(int k=2;k<26;k++){
      a.src[k-2] = d_in[k];
      a.dst[k-2] = (u16*)pp[k];
      a.n[k-2]   = in_sizes[k];
      if(in_sizes[k] > maxn) maxn = in_sizes[k];
    }
    dim3 g((maxn + 255)/256, 24);
    k_cvt_params<<<g, 256, 0, stream>>>(a, flags);
  }

  k_scan1<<<nscan, 256, 0, stream>>>(cnt, Nn, bsum);
  k_scan2<<<1, 1024, 0, stream>>>(bsum, nscan, bpre);
  k_scan3<<<nscan, 256, 0, stream>>>(cnt, Nn, bpre, rowst, cursor, dinv);
  k_scatter8<<<NSL*8, 256, 0, stream>>>(eib, E, Nn, NSL, cursor, dinv, colw);

  const u16* xa = xb;
  for(int i=0; i<7; i++){
    k_gemm3<<<dim3(gblk4,3), 256, 0, stream>>>(xa, Nn,
        cWh + (size_t)i*C*C, cbh + (size_t)i*C, 1, hb,
        cWg + (size_t)i*C*C, (const u16*)nullptr, 0, xwb,
        cWl + (size_t)i*C*C, cbl + (size_t)i*C, 0, xlb);
    k_layer_epi<<<nodeblk, 256, 0, stream>>>(xwb, hb, xlb, colw, rowst, dinv,
        cbg + (size_t)i*C, cbng + (size_t)i*C, cbnb + (size_t)i*C,
        cbnrm + (size_t)i*C, cbnrv + (size_t)i*C,
        clng + (size_t)i*C, clnb + (size_t)i*C,
        cflng, cflnb,
        xlocal, x_cur, Nn, (i==0) ? 1 : 0, (i==6) ? 1 : 0);
    xa = x_cur;
  }

  for(int j=0; j<2; j++){
    k_gemm3<<<dim3(gblk4,3), 256, 0, stream>>>(xg, Nn,
        cgWh + (size_t)j*C*C, cgbh + (size_t)j*C, 0, hb,
        cgWk + (size_t)j*C*C, (const u16*)nullptr, 2, xwb,
        cgWv + (size_t)j*C*C, (const u16*)nullptr, 0, xlb);
    k_kv   <<<NB_KV, 256, 0, stream>>>(xwb, xlb, Nn, npb, kvpart);
    k_kvred<<<(144*128 + 255)/256, 256, 0, stream>>>(kvpart, NB_KV, Bext);
    k_attn <<<gblk, 256, 0, stream>>>(xwb, Bext, hb,
        cglng + (size_t)j*C, cglnb + (size_t)j*C,
        cgWo + (size_t)j*C*C, cgbo + (size_t)j*C,
        cWp, cbp, xg, d_out, Nn, (j==1) ? 1 : 0, flags);
  }
}